// Round 3
// baseline (776.258 us; speedup 1.0000x reference)
//
#include <hip/hip_runtime.h>
#include <cstddef>
#include <cstdint>

#define NB 4
#define NP 8192
#define NK 16
#define NC 128
#define RELW 40    // rel K-extension row stride (elems): 20 dw, conflict-free
#define UINW 264   // UIN row stride: 132 dw % 32 = 4 -> benign

using short8   = __attribute__((ext_vector_type(8))) short;
using ushort4v = __attribute__((ext_vector_type(4))) unsigned short;
using floatx4  = __attribute__((ext_vector_type(4))) float;

__device__ __forceinline__ unsigned short f2bf(float f) {
    union { float f; unsigned u; } v; v.f = f;
    unsigned r = v.u + 0x7FFFu + ((v.u >> 16) & 1u);   // RNE
    return (unsigned short)(r >> 16);
}

// XOR-swizzled 16x/64x128 bf16 tile: phys elem index.
// Reads of 8 consecutive cols at (row, g*8) stay contiguous; bank-uniform.
__device__ __forceinline__ int hsw(int row, int col) {
    return (row << 7) + ((((col >> 3) ^ (row & 15))) << 3) + (col & 7);
}

// async global->LDS, 16 B/lane, dest = wave-uniform base + lane*16
__device__ __forceinline__ void gload16(const void* g, void* l) {
    __builtin_amdgcn_global_load_lds(
        (const __attribute__((address_space(1))) void*)g,
        (__attribute__((address_space(3))) void*)l, 16, 0, 0);
}

#define MFMA(a, b, c) __builtin_amdgcn_mfma_f32_16x16x32_bf16((a), (b), (c), 0, 0, 0)

// ---------------------------------------------------------------------------
// prep: Fbf0 = bf16(features)  +  weight packing (eW1 reordered to
// [feat(128)|rel(3)|pad->160], all others straight fp32->bf16).
// ---------------------------------------------------------------------------
__global__ void prep_k(const float* __restrict__ feat,
                       const float* __restrict__ offW1,
                       const float* __restrict__ eW1,
                       const float* __restrict__ eW2,
                       const float* __restrict__ uW1,
                       const float* __restrict__ uW2,
                       unsigned short* __restrict__ Fbf0,
                       unsigned short* __restrict__ offW1p,
                       unsigned short* __restrict__ eW1p,
                       unsigned short* __restrict__ eW2p,
                       unsigned short* __restrict__ uW1p,
                       unsigned short* __restrict__ uW2p)
{
    int blk = blockIdx.x;
    if (blk < 2048) {
        int i = (blk * 256 + threadIdx.x) * 8;
        float4 f0 = *(const float4*)(feat + i);
        float4 f1 = *(const float4*)(feat + i + 4);
        short8 u;
        u[0] = f2bf(f0.x); u[1] = f2bf(f0.y); u[2] = f2bf(f0.z); u[3] = f2bf(f0.w);
        u[4] = f2bf(f1.x); u[5] = f2bf(f1.y); u[6] = f2bf(f1.z); u[7] = f2bf(f1.w);
        *(short8*)(Fbf0 + i) = u;
        return;
    }
    int i = (blk - 2048) * 256 + threadIdx.x;
    if (i < 16384) { offW1p[i] = f2bf(offW1[i]); return; }
    i -= 16384;
    if (i < 61440) {
        int tt = i / 20480, rem = i % 20480;
        int j = rem / 160, k = rem % 160;
        float v = 0.f;
        if (k < 128)      v = eW1[(tt * 128 + j) * 131 + 3 + k];     // feat part
        else if (k < 131) v = eW1[(tt * 128 + j) * 131 + (k - 128)]; // rel part
        eW1p[i] = f2bf(v);
        return;
    }
    i -= 61440;
    if (i < 49152) { eW2p[i] = f2bf(eW2[i]); return; }
    i -= 49152;
    if (i < 98304) { uW1p[i] = f2bf(uW1[i]); return; }
    i -= 98304;
    if (i < 49152) { uW2p[i] = f2bf(uW2[i]); }
}

// ---------------------------------------------------------------------------
// Fused iteration: offset MLP (inline, MFMA) -> gather(DMA) -> edge MLP ->
// max(K) -> update MLP -> residual; emits fp32 Fout + bf16 FbfN (next iter).
// Block = 256 thr (4 waves), 8 points, edge rows in 2 halves of 64.
// LDS ~29.8 KB.
// ---------------------------------------------------------------------------
__global__ __launch_bounds__(256, 4)
void stab_iter_k(const float* __restrict__ Fin, float* __restrict__ Fout,
                 const unsigned short* __restrict__ Fbf,
                 unsigned short* __restrict__ FbfN,
                 const float* __restrict__ xyz, const int* __restrict__ knn,
                 const unsigned short* __restrict__ offW1p,
                 const float* __restrict__ offW2,
                 const float* __restrict__ offb1,
                 const float* __restrict__ offb2,
                 const unsigned short* __restrict__ eW1p,
                 const unsigned short* __restrict__ eW2p,
                 const float* __restrict__ eb1, const float* __restrict__ eb2,
                 const unsigned short* __restrict__ uW1p,
                 const unsigned short* __restrict__ uW2p,
                 const float* __restrict__ ub1, const float* __restrict__ ub2)
{
    __shared__ __align__(16) unsigned short s_EIF[8192];       // 16384 B: gathered feats / H / UIN
    __shared__ __align__(16) unsigned short s_REL[64 * RELW];  //  5120 B: rel K-ext / HOFF / H2
    __shared__ __align__(16) float s_AGG[8 * NC];              //  4096 B: agg / OFFA (bf16 alias)
    __shared__ __align__(16) float s_FSELF[8 * NC];            //  4096 B
    __shared__ float s_CTR[8][3];

    const int xcd  = blockIdx.x & 7;
    const int slot = blockIdx.x >> 3;
    const int b    = xcd >> 1;
    const int n0   = ((slot << 1) | (xcd & 1)) << 3;
    const int t = threadIdx.x, wv = t >> 6, ln = t & 63;
    const int q = ln >> 4, r = ln & 15, cg0 = wv << 1;
    const int gk = (wv << 2) + (ln >> 4);       // this lane's neighbor index k
    const int gg = ((ln & 15) ^ gk) << 3;       // gather source column (elems)
    const size_t rowbase = (size_t)b * NP + n0;

    // ---------------- stage 0: idx prefetch, DMA half0, self feats ----------
    int idx[8];
#pragma unroll
    for (int p = 0; p < 8; ++p)
        idx[p] = knn[(rowbase + p) * NK + gk];
#pragma unroll
    for (int pass = 0; pass < 4; ++pass)
        gload16(Fbf + ((size_t)b * NP + idx[pass]) * NC + gg,
                (char*)s_EIF + pass * 4096 + wv * 1024);

    unsigned short* OFFA = (unsigned short*)s_AGG;
    {
        int row = t >> 5, c4 = (t & 31) << 2;
        float4 f = *(const float4*)(Fin + (rowbase + row) * NC + c4);
        *(float4*)&s_FSELF[row * NC + c4] = f;
        ushort4v u = { f2bf(f.x), f2bf(f.y), f2bf(f.z), f2bf(f.w) };
        *(ushort4v*)&OFFA[hsw(row, c4)] = u;
        ushort4v z = {0, 0, 0, 0};
        *(ushort4v*)&OFFA[hsw(row + 8, c4)] = z;   // zero pad rows 8..15
    }
    float xnb0[4][3];
    if (r == 0) {   // neighbor xyz prefetch for half0 rel
#pragma unroll
        for (int pass = 0; pass < 4; ++pass) {
            const float* xp = xyz + ((size_t)b * NP + idx[pass]) * 3;
            xnb0[pass][0] = xp[0]; xnb0[pass][1] = xp[1]; xnb0[pass][2] = xp[2];
        }
    }
    short8 wf1[2][5];   // edge L1 weights: persistent across both halves
#pragma unroll
    for (int c = 0; c < 2; ++c)
#pragma unroll
        for (int ks = 0; ks < 5; ++ks)
            wf1[c][ks] = *(const short8*)(eW1p + ((cg0 + c) * 16 + r) * 160 + ks * 32 + q * 8);
    float eb1v[2] = { eb1[cg0 * 16 + r], eb1[(cg0 + 1) * 16 + r] };
    float eb2v[2] = { eb2[cg0 * 16 + r], eb2[(cg0 + 1) * 16 + r] };
    __syncthreads();   // B1: OFFA/FSELF ready (also drains half0 DMA)

    // ---------------- offset MLP layer 1 -> HOFF ----------------
    unsigned short* HOFF = s_REL;
    {
        short8 wf[2][4];
#pragma unroll
        for (int c = 0; c < 2; ++c)
#pragma unroll
            for (int ks = 0; ks < 4; ++ks)
                wf[c][ks] = *(const short8*)(offW1p + ((cg0 + c) * 16 + r) * NC + ks * 32 + q * 8);
        short8 af[4];
#pragma unroll
        for (int ks = 0; ks < 4; ++ks)
            af[ks] = *(const short8*)&OFFA[hsw(r, ks * 32 + q * 8)];
        floatx4 acc[2] = { {0.f,0.f,0.f,0.f}, {0.f,0.f,0.f,0.f} };
#pragma unroll
        for (int c = 0; c < 2; ++c)
#pragma unroll
            for (int ks = 0; ks < 4; ++ks)
                acc[c] = MFMA(af[ks], wf[c][ks], acc[c]);
#pragma unroll
        for (int c = 0; c < 2; ++c) {
            int col = (cg0 + c) * 16 + r;
            float bv = offb1[col];
#pragma unroll
            for (int i = 0; i < 4; ++i)
                HOFF[hsw(q * 4 + i, col)] = f2bf(fmaxf(acc[c][i] + bv, 0.f));
        }
    }
    __syncthreads();   // B2: HOFF ready

    // ---------------- offset MLP layer 2 (wave 0) -> centers ----------------
    if (wv == 0) {
        short8 wf[4];
#pragma unroll
        for (int ks = 0; ks < 4; ++ks) {
            short8 u = {0,0,0,0,0,0,0,0};
            if (r < 3) {
                const float* w = offW2 + r * NC + ks * 32 + q * 8;
                float4 f0 = *(const float4*)w;
                float4 f1 = *(const float4*)(w + 4);
                u[0] = f2bf(f0.x); u[1] = f2bf(f0.y); u[2] = f2bf(f0.z); u[3] = f2bf(f0.w);
                u[4] = f2bf(f1.x); u[5] = f2bf(f1.y); u[6] = f2bf(f1.z); u[7] = f2bf(f1.w);
            }
            wf[ks] = u;
        }
        short8 af[4];
#pragma unroll
        for (int ks = 0; ks < 4; ++ks)
            af[ks] = *(const short8*)&HOFF[hsw(r, ks * 32 + q * 8)];
        floatx4 acc = {0.f, 0.f, 0.f, 0.f};
#pragma unroll
        for (int ks = 0; ks < 4; ++ks)
            acc = MFMA(af[ks], wf[ks], acc);
        if (r < 3 && q < 2) {
#pragma unroll
            for (int i = 0; i < 4; ++i) {
                int p = q * 4 + i;
                s_CTR[p][r] = xyz[(rowbase + p) * 3 + r] + acc[i] + offb2[r];
            }
        }
    }
    __syncthreads();   // B3: centers ready (HOFF dead)

    // zero rel K-ext pads (elems 4..31; read by ks=4, killed by W1p zeros
    // anyway but must be finite)
    if (t < 64) {
        ushort4v z = {0, 0, 0, 0};
#pragma unroll
        for (int gz = 1; gz < 8; ++gz)
            *(ushort4v*)&s_REL[t * RELW + gz * 4] = z;
    }

    // ---------------- edge phase: 2 halves of 64 rows ----------------
    float xnb1[4][3];
#pragma unroll
    for (int h = 0; h < 2; ++h) {
        if (h == 1) {   // DMA half1 (region free after barrier D of half0)
#pragma unroll
            for (int pass = 0; pass < 4; ++pass)
                gload16(Fbf + ((size_t)b * NP + idx[4 + pass]) * NC + gg,
                        (char*)s_EIF + pass * 4096 + wv * 1024);
        }
        if (r == 0) {   // rel-pos -> s_REL
#pragma unroll
            for (int pass = 0; pass < 4; ++pass) {
                int p = (h << 2) + pass;
                int row = (pass << 4) + gk;
                const float* xv = (h == 0) ? xnb0[pass] : xnb1[pass];
                ushort4v rv = { f2bf(xv[0] - s_CTR[p][0]),
                                f2bf(xv[1] - s_CTR[p][1]),
                                f2bf(xv[2] - s_CTR[p][2]), 0 };
                *(ushort4v*)&s_REL[row * RELW] = rv;
            }
        }
        __syncthreads();   // A: edge inputs ready (drains DMA)

        // ---- edge L1
        floatx4 acc1[4][2];
#pragma unroll
        for (int rt = 0; rt < 4; ++rt) {
            short8 af[5];
            int rowb = (rt * 16 + r) << 7;
#pragma unroll
            for (int ks = 0; ks < 4; ++ks)
                af[ks] = *(const short8*)&s_EIF[rowb + ((((ks << 2) + q) ^ r) << 3)];
            af[4] = *(const short8*)&s_REL[(rt * 16 + r) * RELW + q * 8];
            acc1[rt][0] = (floatx4){0.f,0.f,0.f,0.f};
            acc1[rt][1] = (floatx4){0.f,0.f,0.f,0.f};
#pragma unroll
            for (int c = 0; c < 2; ++c)
#pragma unroll
                for (int ks = 0; ks < 5; ++ks)
                    acc1[rt][c] = MFMA(af[ks], wf1[c][ks], acc1[rt][c]);
        }
        __syncthreads();   // B: inputs consumed; H aliases s_EIF

        // ---- bias+relu -> H (swizzled bf16)
#pragma unroll
        for (int rt = 0; rt < 4; ++rt)
#pragma unroll
            for (int c = 0; c < 2; ++c) {
                int col = (cg0 + c) * 16 + r;
#pragma unroll
                for (int i = 0; i < 4; ++i)
                    s_EIF[hsw(rt * 16 + q * 4 + i, col)] =
                        f2bf(fmaxf(acc1[rt][c][i] + eb1v[c], 0.f));
            }
        __syncthreads();   // C: H ready

        // ---- edge L2 + max over K
        {
            short8 wf2[2][4];
#pragma unroll
            for (int c = 0; c < 2; ++c)
#pragma unroll
                for (int ks = 0; ks < 4; ++ks)
                    wf2[c][ks] = *(const short8*)(eW2p + ((cg0 + c) * 16 + r) * NC + ks * 32 + q * 8);
            if (h == 0 && r == 0) {   // prefetch half1 neighbor xyz
#pragma unroll
                for (int pass = 0; pass < 4; ++pass) {
                    const float* xp = xyz + ((size_t)b * NP + idx[4 + pass]) * 3;
                    xnb1[pass][0] = xp[0]; xnb1[pass][1] = xp[1]; xnb1[pass][2] = xp[2];
                }
            }
#pragma unroll
            for (int rt = 0; rt < 4; ++rt) {
                short8 af[4];
                int rowb = (rt * 16 + r) << 7;
#pragma unroll
                for (int ks = 0; ks < 4; ++ks)
                    af[ks] = *(const short8*)&s_EIF[rowb + ((((ks << 2) + q) ^ r) << 3)];
                floatx4 acc[2] = { {0.f,0.f,0.f,0.f}, {0.f,0.f,0.f,0.f} };
#pragma unroll
                for (int c = 0; c < 2; ++c)
#pragma unroll
                    for (int ks = 0; ks < 4; ++ks)
                        acc[c] = MFMA(af[ks], wf2[c][ks], acc[c]);
#pragma unroll
                for (int c = 0; c < 2; ++c) {
                    float m = fmaxf(fmaxf(acc[c][0], acc[c][1]),
                                    fmaxf(acc[c][2], acc[c][3]));
                    m = fmaxf(m, __shfl_xor(m, 16));
                    m = fmaxf(m, __shfl_xor(m, 32));
                    if (q == 0)
                        s_AGG[((h << 2) + rt) * NC + (cg0 + c) * 16 + r] = m + eb2v[c];
                }
            }
        }
        __syncthreads();   // D: H consumed
    }

    // ---------------- UIN assembly [agg | self] (float4 reads: bank-uniform)
    {
        int p = t >> 5, c4 = (t & 31) << 2;
        float4 a = *(const float4*)&s_AGG[p * NC + c4];
        float4 f = *(const float4*)&s_FSELF[p * NC + c4];
        ushort4v ua = { f2bf(a.x), f2bf(a.y), f2bf(a.z), f2bf(a.w) };
        ushort4v uf = { f2bf(f.x), f2bf(f.y), f2bf(f.z), f2bf(f.w) };
        *(ushort4v*)&s_EIF[p * UINW + c4] = ua;
        *(ushort4v*)&s_EIF[p * UINW + 128 + c4] = uf;
    }
    __syncthreads();

    // ---------------- update L1 (K=256) -> H2 (s_REL, swizzled)
    {
        short8 wf[2][8];
#pragma unroll
        for (int c = 0; c < 2; ++c)
#pragma unroll
            for (int ks = 0; ks < 8; ++ks)
                wf[c][ks] = *(const short8*)(uW1p + ((cg0 + c) * 16 + r) * 256 + ks * 32 + q * 8);
        short8 af[8];
#pragma unroll
        for (int ks = 0; ks < 8; ++ks)
            af[ks] = *(const short8*)&s_EIF[r * UINW + ks * 32 + q * 8];
        floatx4 acc[2] = { {0.f,0.f,0.f,0.f}, {0.f,0.f,0.f,0.f} };
#pragma unroll
        for (int c = 0; c < 2; ++c)
#pragma unroll
            for (int ks = 0; ks < 8; ++ks)
                acc[c] = MFMA(af[ks], wf[c][ks], acc[c]);
#pragma unroll
        for (int c = 0; c < 2; ++c) {
            int col = (cg0 + c) * 16 + r;
            float bv = ub1[col];
#pragma unroll
            for (int i = 0; i < 4; ++i)
                s_REL[hsw(q * 4 + i, col)] = f2bf(fmaxf(acc[c][i] + bv, 0.f));
        }
    }
    __syncthreads();

    // ---------------- update L2 + residual -> Fout (fp32) + FbfN (bf16)
    {
        short8 wf[2][4];
#pragma unroll
        for (int c = 0; c < 2; ++c)
#pragma unroll
            for (int ks = 0; ks < 4; ++ks)
                wf[c][ks] = *(const short8*)(uW2p + ((cg0 + c) * 16 + r) * NC + ks * 32 + q * 8);
        short8 af[4];
#pragma unroll
        for (int ks = 0; ks < 4; ++ks)
            af[ks] = *(const short8*)&s_REL[hsw(r, ks * 32 + q * 8)];
        floatx4 acc[2] = { {0.f,0.f,0.f,0.f}, {0.f,0.f,0.f,0.f} };
#pragma unroll
        for (int c = 0; c < 2; ++c)
#pragma unroll
            for (int ks = 0; ks < 4; ++ks)
                acc[c] = MFMA(af[ks], wf[c][ks], acc[c]);
        if (q < 2) {
#pragma unroll
            for (int c = 0; c < 2; ++c) {
                int col = (cg0 + c) * 16 + r;
                float bv = ub2[col];
#pragma unroll
                for (int i = 0; i < 4; ++i) {
                    int p = q * 4 + i;   // 0..7
                    float v = s_FSELF[p * NC + col] + acc[c][i] + bv;
                    Fout[(rowbase + p) * NC + col] = v;
                    FbfN[(rowbase + p) * NC + col] = f2bf(v);
                }
            }
        }
    }
}

// ---------------------------------------------------------------------------
extern "C" void kernel_launch(void* const* d_in, const int* in_sizes, int n_in,
                              void* d_out, int out_size, void* d_ws, size_t ws_size,
                              hipStream_t stream)
{
    const float* xyz   = (const float*)d_in[0];
    const float* feat  = (const float*)d_in[1];
    const int*   knn   = (const int*)d_in[2];
    const float* offW1 = (const float*)d_in[3];
    const float* offb1 = (const float*)d_in[4];
    const float* offW2 = (const float*)d_in[5];
    const float* offb2 = (const float*)d_in[6];
    const float* eW1   = (const float*)d_in[7];
    const float* eb1   = (const float*)d_in[8];
    const float* eW2   = (const float*)d_in[9];
    const float* eb2   = (const float*)d_in[10];
    const float* uW1   = (const float*)d_in[11];
    const float* ub1   = (const float*)d_in[12];
    const float* uW2   = (const float*)d_in[13];
    const float* ub2   = (const float*)d_in[14];
    float* out = (float*)d_out;

    char* ws = (char*)d_ws;
    unsigned short* FbfA   = (unsigned short*)ws;                 //  8388608 B
    unsigned short* FbfB   = (unsigned short*)(ws + 8388608);     //  8388608 B
    unsigned short* offW1p = (unsigned short*)(ws + 16777216);    //    32768 B
    unsigned short* eW1p   = (unsigned short*)(ws + 16809984);    //   122880 B
    unsigned short* eW2p   = (unsigned short*)(ws + 16932864);    //    98304 B
    unsigned short* uW1p   = (unsigned short*)(ws + 17031168);    //   196608 B
    unsigned short* uW2p   = (unsigned short*)(ws + 17227776);    //    98304 B

    prep_k<<<3120, 256, 0, stream>>>(feat, offW1, eW1, eW2, uW1, uW2,
                                     FbfA, offW1p, eW1p, eW2p, uW1p, uW2p);

    // fp32 features: feat -> d_out, then in place (own rows only; gathers use
    // the bf16 ping-pong copies).
    const float*          fin[3]  = { feat, out,  out  };
    const unsigned short* fbf[3]  = { FbfA, FbfB, FbfA };
    unsigned short*       fbn[3]  = { FbfB, FbfA, FbfB };
    for (int tt = 0; tt < 3; ++tt) {
        stab_iter_k<<<4096, 256, 0, stream>>>(
            fin[tt], out, fbf[tt], fbn[tt], xyz, knn,
            offW1p, offW2, offb1, offb2,
            eW1p + tt * 20480, eW2p + tt * 16384, eb1 + tt * 128, eb2 + tt * 128,
            uW1p + tt * 32768, uW2p + tt * 16384, ub1 + tt * 128, ub2 + tt * 128);
    }
}

// Round 4
// 681.793 us; speedup vs baseline: 1.1386x; 1.1386x over previous
//
#include <hip/hip_runtime.h>
#include <cstddef>
#include <cstdint>

#define NB 4
#define NP 8192
#define NK 16
#define NC 128
#define RELW 40    // rel K-extension row stride (elems): 20 dw, conflict-free
#define UINW 264   // UIN row stride: 132 dw % 32 = 4 -> benign

using short8   = __attribute__((ext_vector_type(8))) short;
using ushort4v = __attribute__((ext_vector_type(4))) unsigned short;
using floatx4  = __attribute__((ext_vector_type(4))) float;

__device__ __forceinline__ unsigned short f2bf(float f) {
    union { float f; unsigned u; } v; v.f = f;
    unsigned r = v.u + 0x7FFFu + ((v.u >> 16) & 1u);   // RNE
    return (unsigned short)(r >> 16);
}

// XOR-swizzled (rows x 128) bf16 tile, phys elem index. 8-col groups stay
// contiguous (b128-friendly); col-group ^= (row&15) spreads banks uniformly.
__device__ __forceinline__ int hsw(int row, int col) {
    return (row << 7) + ((((col >> 3) ^ (row & 15))) << 3) + (col & 7);
}

#define MFMA(a, b, c) __builtin_amdgcn_mfma_f32_16x16x32_bf16((a), (b), (c), 0, 0, 0)

// ---------------------------------------------------------------------------
// prep: Fbf0 = bf16(features)  +  weight packing (eW1 reordered to
// [feat(128)|rel(3)|pad->160], all others straight fp32->bf16).
// ---------------------------------------------------------------------------
__global__ void prep_k(const float* __restrict__ feat,
                       const float* __restrict__ offW1,
                       const float* __restrict__ eW1,
                       const float* __restrict__ eW2,
                       const float* __restrict__ uW1,
                       const float* __restrict__ uW2,
                       unsigned short* __restrict__ Fbf0,
                       unsigned short* __restrict__ offW1p,
                       unsigned short* __restrict__ eW1p,
                       unsigned short* __restrict__ eW2p,
                       unsigned short* __restrict__ uW1p,
                       unsigned short* __restrict__ uW2p)
{
    int blk = blockIdx.x;
    if (blk < 2048) {
        int i = (blk * 256 + threadIdx.x) * 8;
        float4 f0 = *(const float4*)(feat + i);
        float4 f1 = *(const float4*)(feat + i + 4);
        short8 u;
        u[0] = f2bf(f0.x); u[1] = f2bf(f0.y); u[2] = f2bf(f0.z); u[3] = f2bf(f0.w);
        u[4] = f2bf(f1.x); u[5] = f2bf(f1.y); u[6] = f2bf(f1.z); u[7] = f2bf(f1.w);
        *(short8*)(Fbf0 + i) = u;
        return;
    }
    int i = (blk - 2048) * 256 + threadIdx.x;
    if (i < 16384) { offW1p[i] = f2bf(offW1[i]); return; }
    i -= 16384;
    if (i < 61440) {
        int tt = i / 20480, rem = i % 20480;
        int j = rem / 160, k = rem % 160;
        float v = 0.f;
        if (k < 128)      v = eW1[(tt * 128 + j) * 131 + 3 + k];     // feat part
        else if (k < 131) v = eW1[(tt * 128 + j) * 131 + (k - 128)]; // rel part
        eW1p[i] = f2bf(v);
        return;
    }
    i -= 61440;
    if (i < 49152) { eW2p[i] = f2bf(eW2[i]); return; }
    i -= 49152;
    if (i < 98304) { uW1p[i] = f2bf(uW1[i]); return; }
    i -= 98304;
    if (i < 49152) { uW2p[i] = f2bf(uW2[i]); }
}

// ---------------------------------------------------------------------------
// Fused iteration: offset MLP (MFMA) -> gather(bf16, VGPR) -> edge MLP ->
// max(K) -> update MLP -> residual; emits fp32 Fout + bf16 FbfN (next iter).
// Block = 256 thr (4 waves), 8 points, edge rows in 2 halves of 64.
// LDS ~29.8 KB -> 4 blocks/CU. No per-thread arrays with address exposure
// (round-3 scratch-spill lesson): all xyz/knn accessed directly at use.
// ---------------------------------------------------------------------------
__global__ __launch_bounds__(256, 4)
void stab_iter_k(const float* __restrict__ Fin, float* __restrict__ Fout,
                 const unsigned short* __restrict__ Fbf,
                 unsigned short* __restrict__ FbfN,
                 const float* __restrict__ xyz, const int* __restrict__ knn,
                 const unsigned short* __restrict__ offW1p,
                 const float* __restrict__ offW2,
                 const float* __restrict__ offb1,
                 const float* __restrict__ offb2,
                 const unsigned short* __restrict__ eW1p,
                 const unsigned short* __restrict__ eW2p,
                 const float* __restrict__ eb1, const float* __restrict__ eb2,
                 const unsigned short* __restrict__ uW1p,
                 const unsigned short* __restrict__ uW2p,
                 const float* __restrict__ ub1, const float* __restrict__ ub2)
{
    __shared__ __align__(16) unsigned short s_EIF[64 * NC];    // 16384 B: feats / H / UIN
    __shared__ __align__(16) unsigned short s_REL[64 * RELW];  //  5120 B: rel / HOFF / H2
    __shared__ __align__(16) float s_AGG[8 * NC];              //  4096 B: agg (OFFA alias)
    __shared__ __align__(16) float s_FSELF[8 * NC];            //  4096 B
    __shared__ int   s_KNN[128];                               //   512 B
    __shared__ float s_CTR[8][3];                              //    96 B

    const int xcd  = blockIdx.x & 7;
    const int slot = blockIdx.x >> 3;
    const int b    = xcd >> 1;
    const int n0   = ((slot << 1) | (xcd & 1)) << 3;
    const int t = threadIdx.x, wv = t >> 6, ln = t & 63;
    const int q = ln >> 4, r = ln & 15, cg0 = wv << 1;
    const size_t rowbase = (size_t)b * NP + n0;

    // ---------------- stage 0: self feats + knn ----------------
    unsigned short* OFFA = (unsigned short*)s_AGG;   // 16x128 swizzled bf16
    {
        int row = t >> 5, c4 = (t & 31) << 2;
        float4 f = *(const float4*)(Fin + (rowbase + row) * NC + c4);
        *(float4*)&s_FSELF[row * NC + c4] = f;
        ushort4v u = { f2bf(f.x), f2bf(f.y), f2bf(f.z), f2bf(f.w) };
        *(ushort4v*)&OFFA[hsw(row, c4)] = u;
        ushort4v z = {0, 0, 0, 0};
        *(ushort4v*)&OFFA[hsw(row + 8, c4)] = z;     // zero rows 8..15
        if (t < 128)
            s_KNN[t] = knn[(rowbase + (t >> 4)) * NK + (t & 15)];
    }
    // persistent edge L1 weight frags + biases
    short8 wf1[2][5];
#pragma unroll
    for (int c = 0; c < 2; ++c)
#pragma unroll
        for (int ks = 0; ks < 5; ++ks)
            wf1[c][ks] = *(const short8*)(eW1p + ((cg0 + c) * 16 + r) * 160 + ks * 32 + q * 8);
    float eb1v[2] = { eb1[cg0 * 16 + r], eb1[(cg0 + 1) * 16 + r] };
    float eb2v[2] = { eb2[cg0 * 16 + r], eb2[(cg0 + 1) * 16 + r] };
    __syncthreads();   // B1: OFFA/FSELF/KNN ready

    // ---------------- offset MLP layer 1 -> HOFF (s_REL, swizzled) ----------
    unsigned short* HOFF = s_REL;
    {
        short8 wf[2][4];
#pragma unroll
        for (int c = 0; c < 2; ++c)
#pragma unroll
            for (int ks = 0; ks < 4; ++ks)
                wf[c][ks] = *(const short8*)(offW1p + ((cg0 + c) * 16 + r) * NC + ks * 32 + q * 8);
        short8 af[4];
#pragma unroll
        for (int ks = 0; ks < 4; ++ks)
            af[ks] = *(const short8*)&OFFA[hsw(r, ks * 32 + q * 8)];
        floatx4 acc[2] = { {0.f,0.f,0.f,0.f}, {0.f,0.f,0.f,0.f} };
#pragma unroll
        for (int c = 0; c < 2; ++c)
#pragma unroll
            for (int ks = 0; ks < 4; ++ks)
                acc[c] = MFMA(af[ks], wf[c][ks], acc[c]);
#pragma unroll
        for (int c = 0; c < 2; ++c) {
            int col = (cg0 + c) * 16 + r;
            float bv = offb1[col];
#pragma unroll
            for (int i = 0; i < 4; ++i)
                HOFF[hsw(q * 4 + i, col)] = f2bf(fmaxf(acc[c][i] + bv, 0.f));
        }
    }
    __syncthreads();   // B2: HOFF ready

    // ---------------- offset MLP layer 2 (wave 0) -> centers ----------------
    if (wv == 0) {
        short8 wf[4];
#pragma unroll
        for (int ks = 0; ks < 4; ++ks) {
            short8 u = {0,0,0,0,0,0,0,0};
            if (r < 3) {
                const float* w = offW2 + r * NC + ks * 32 + q * 8;
                float4 f0 = *(const float4*)w;
                float4 f1 = *(const float4*)(w + 4);
                u[0] = f2bf(f0.x); u[1] = f2bf(f0.y); u[2] = f2bf(f0.z); u[3] = f2bf(f0.w);
                u[4] = f2bf(f1.x); u[5] = f2bf(f1.y); u[6] = f2bf(f1.z); u[7] = f2bf(f1.w);
            }
            wf[ks] = u;
        }
        short8 af[4];
#pragma unroll
        for (int ks = 0; ks < 4; ++ks)
            af[ks] = *(const short8*)&HOFF[hsw(r, ks * 32 + q * 8)];
        floatx4 acc = {0.f, 0.f, 0.f, 0.f};
#pragma unroll
        for (int ks = 0; ks < 4; ++ks)
            acc = MFMA(af[ks], wf[ks], acc);
        if (r < 3 && q < 2) {
#pragma unroll
            for (int i = 0; i < 4; ++i) {
                int p = q * 4 + i;
                s_CTR[p][r] = xyz[(rowbase + p) * 3 + r] + acc[i] + offb2[r];
            }
        }
    }
    __syncthreads();   // B3: centers ready (HOFF dead)

    // zero rel K-ext pads (elems 4..31 per row; multiplied by W1p zero rows,
    // but must be finite bf16)
    if (t < 64) {
        ushort4v z = {0, 0, 0, 0};
#pragma unroll
        for (int gz = 1; gz < 8; ++gz)
            *(ushort4v*)&s_REL[t * RELW + gz * 4] = z;
    }

    // ---------------- edge phase: 2 halves of 64 rows ----------------
#pragma unroll
    for (int h = 0; h < 2; ++h) {
        // gather 64 rows of bf16 features (VGPR-mediated, swizzled LDS write)
        {
            int rr = t >> 4, c8 = (t & 15) * 8;
#pragma unroll
            for (int pass = 0; pass < 4; ++pass) {
                int row64 = pass * 16 + rr;
                int nb = s_KNN[h * 64 + row64];
                short8 u = *(const short8*)(Fbf + ((size_t)b * NP + nb) * NC + c8);
                *(short8*)&s_EIF[hsw(row64, c8)] = u;
            }
        }
        if (t < 64) {   // rel-pos, direct loads (no local arrays!)
            int row64 = t, p = (h << 2) + (t >> 4);
            int nb = s_KNN[h * 64 + row64];
            const float* xp = xyz + ((size_t)b * NP + nb) * 3;
            ushort4v rv = { f2bf(xp[0] - s_CTR[p][0]), f2bf(xp[1] - s_CTR[p][1]),
                            f2bf(xp[2] - s_CTR[p][2]), 0 };
            *(ushort4v*)&s_REL[row64 * RELW] = rv;
        }
        __syncthreads();   // A: edge inputs ready

        // ---- edge L1
        floatx4 acc1[4][2];
#pragma unroll
        for (int rt = 0; rt < 4; ++rt) {
            short8 af[5];
            int rowb = (rt * 16 + r) << 7;
#pragma unroll
            for (int ks = 0; ks < 4; ++ks)
                af[ks] = *(const short8*)&s_EIF[rowb + ((((ks << 2) + q) ^ r) << 3)];
            af[4] = *(const short8*)&s_REL[(rt * 16 + r) * RELW + q * 8];
            acc1[rt][0] = (floatx4){0.f,0.f,0.f,0.f};
            acc1[rt][1] = (floatx4){0.f,0.f,0.f,0.f};
#pragma unroll
            for (int c = 0; c < 2; ++c)
#pragma unroll
                for (int ks = 0; ks < 5; ++ks)
                    acc1[rt][c] = MFMA(af[ks], wf1[c][ks], acc1[rt][c]);
        }
        __syncthreads();   // B: inputs consumed; H aliases s_EIF

        // ---- bias+relu -> H (swizzled bf16)
#pragma unroll
        for (int rt = 0; rt < 4; ++rt)
#pragma unroll
            for (int c = 0; c < 2; ++c) {
                int col = (cg0 + c) * 16 + r;
#pragma unroll
                for (int i = 0; i < 4; ++i)
                    s_EIF[hsw(rt * 16 + q * 4 + i, col)] =
                        f2bf(fmaxf(acc1[rt][c][i] + eb1v[c], 0.f));
            }
        __syncthreads();   // C: H ready

        // ---- edge L2 + max over K (16-row tile = one point)
        {
            short8 wf2[2][4];
#pragma unroll
            for (int c = 0; c < 2; ++c)
#pragma unroll
                for (int ks = 0; ks < 4; ++ks)
                    wf2[c][ks] = *(const short8*)(eW2p + ((cg0 + c) * 16 + r) * NC + ks * 32 + q * 8);
#pragma unroll
            for (int rt = 0; rt < 4; ++rt) {
                short8 af[4];
                int rowb = (rt * 16 + r) << 7;
#pragma unroll
                for (int ks = 0; ks < 4; ++ks)
                    af[ks] = *(const short8*)&s_EIF[rowb + ((((ks << 2) + q) ^ r) << 3)];
                floatx4 acc[2] = { {0.f,0.f,0.f,0.f}, {0.f,0.f,0.f,0.f} };
#pragma unroll
                for (int c = 0; c < 2; ++c)
#pragma unroll
                    for (int ks = 0; ks < 4; ++ks)
                        acc[c] = MFMA(af[ks], wf2[c][ks], acc[c]);
#pragma unroll
                for (int c = 0; c < 2; ++c) {
                    float m = fmaxf(fmaxf(acc[c][0], acc[c][1]),
                                    fmaxf(acc[c][2], acc[c][3]));
                    m = fmaxf(m, __shfl_xor(m, 16));
                    m = fmaxf(m, __shfl_xor(m, 32));
                    if (q == 0)
                        s_AGG[((h << 2) + rt) * NC + (cg0 + c) * 16 + r] = m + eb2v[c];
                }
            }
        }
        __syncthreads();   // D: H consumed
    }

    // ---------------- UIN assembly [agg | self] (float4 reads)
    {
        int p = t >> 5, c4 = (t & 31) << 2;
        float4 a = *(const float4*)&s_AGG[p * NC + c4];
        float4 f = *(const float4*)&s_FSELF[p * NC + c4];
        ushort4v ua = { f2bf(a.x), f2bf(a.y), f2bf(a.z), f2bf(a.w) };
        ushort4v uf = { f2bf(f.x), f2bf(f.y), f2bf(f.z), f2bf(f.w) };
        *(ushort4v*)&s_EIF[p * UINW + c4] = ua;
        *(ushort4v*)&s_EIF[p * UINW + 128 + c4] = uf;
    }
    __syncthreads();

    // ---------------- update L1 (K=256) -> H2 (s_REL, swizzled)
    {
        short8 wf[2][8];
#pragma unroll
        for (int c = 0; c < 2; ++c)
#pragma unroll
            for (int ks = 0; ks < 8; ++ks)
                wf[c][ks] = *(const short8*)(uW1p + ((cg0 + c) * 16 + r) * 256 + ks * 32 + q * 8);
        short8 af[8];
#pragma unroll
        for (int ks = 0; ks < 8; ++ks)
            af[ks] = *(const short8*)&s_EIF[r * UINW + ks * 32 + q * 8];
        floatx4 acc[2] = { {0.f,0.f,0.f,0.f}, {0.f,0.f,0.f,0.f} };
#pragma unroll
        for (int c = 0; c < 2; ++c)
#pragma unroll
            for (int ks = 0; ks < 8; ++ks)
                acc[c] = MFMA(af[ks], wf[c][ks], acc[c]);
#pragma unroll
        for (int c = 0; c < 2; ++c) {
            int col = (cg0 + c) * 16 + r;
            float bv = ub1[col];
#pragma unroll
            for (int i = 0; i < 4; ++i)
                s_REL[hsw(q * 4 + i, col)] = f2bf(fmaxf(acc[c][i] + bv, 0.f));
        }
    }
    __syncthreads();

    // ---------------- update L2 + residual -> Fout (fp32) + FbfN (bf16)
    {
        short8 wf[2][4];
#pragma unroll
        for (int c = 0; c < 2; ++c)
#pragma unroll
            for (int ks = 0; ks < 4; ++ks)
                wf[c][ks] = *(const short8*)(uW2p + ((cg0 + c) * 16 + r) * NC + ks * 32 + q * 8);
        short8 af[4];
#pragma unroll
        for (int ks = 0; ks < 4; ++ks)
            af[ks] = *(const short8*)&s_REL[hsw(r, ks * 32 + q * 8)];
        floatx4 acc[2] = { {0.f,0.f,0.f,0.f}, {0.f,0.f,0.f,0.f} };
#pragma unroll
        for (int c = 0; c < 2; ++c)
#pragma unroll
            for (int ks = 0; ks < 4; ++ks)
                acc[c] = MFMA(af[ks], wf[c][ks], acc[c]);
        if (q < 2) {
#pragma unroll
            for (int c = 0; c < 2; ++c) {
                int col = (cg0 + c) * 16 + r;
                float bv = ub2[col];
#pragma unroll
                for (int i = 0; i < 4; ++i) {
                    int p = q * 4 + i;   // 0..7
                    float v = s_FSELF[p * NC + col] + acc[c][i] + bv;
                    Fout[(rowbase + p) * NC + col] = v;
                    FbfN[(rowbase + p) * NC + col] = f2bf(v);
                }
            }
        }
    }
}

// ---------------------------------------------------------------------------
extern "C" void kernel_launch(void* const* d_in, const int* in_sizes, int n_in,
                              void* d_out, int out_size, void* d_ws, size_t ws_size,
                              hipStream_t stream)
{
    const float* xyz   = (const float*)d_in[0];
    const float* feat  = (const float*)d_in[1];
    const int*   knn   = (const int*)d_in[2];
    const float* offW1 = (const float*)d_in[3];
    const float* offb1 = (const float*)d_in[4];
    const float* offW2 = (const float*)d_in[5];
    const float* offb2 = (const float*)d_in[6];
    const float* eW1   = (const float*)d_in[7];
    const float* eb1   = (const float*)d_in[8];
    const float* eW2   = (const float*)d_in[9];
    const float* eb2   = (const float*)d_in[10];
    const float* uW1   = (const float*)d_in[11];
    const float* ub1   = (const float*)d_in[12];
    const float* uW2   = (const float*)d_in[13];
    const float* ub2   = (const float*)d_in[14];
    float* out = (float*)d_out;

    char* ws = (char*)d_ws;
    unsigned short* FbfA   = (unsigned short*)ws;                 //  8388608 B
    unsigned short* FbfB   = (unsigned short*)(ws + 8388608);     //  8388608 B
    unsigned short* offW1p = (unsigned short*)(ws + 16777216);    //    32768 B
    unsigned short* eW1p   = (unsigned short*)(ws + 16809984);    //   122880 B
    unsigned short* eW2p   = (unsigned short*)(ws + 16932864);    //    98304 B
    unsigned short* uW1p   = (unsigned short*)(ws + 17031168);    //   196608 B
    unsigned short* uW2p   = (unsigned short*)(ws + 17227776);    //    98304 B

    prep_k<<<3120, 256, 0, stream>>>(feat, offW1, eW1, eW2, uW1, uW2,
                                     FbfA, offW1p, eW1p, eW2p, uW1p, uW2p);

    // fp32 features: feat -> d_out, then in place (own rows only; gathers use
    // the bf16 ping-pong copies emitted by the previous iteration).
    const float*          fin[3] = { feat, out,  out  };
    const unsigned short* fbf[3] = { FbfA, FbfB, FbfA };
    unsigned short*       fbn[3] = { FbfB, FbfA, FbfB };
    for (int tt = 0; tt < 3; ++tt) {
        stab_iter_k<<<4096, 256, 0, stream>>>(
            fin[tt], out, fbf[tt], fbn[tt], xyz, knn,
            offW1p, offW2, offb1, offb2,
            eW1p + tt * 20480, eW2p + tt * 16384, eb1 + tt * 128, eb2 + tt * 128,
            uW1p + tt * 32768, uW2p + tt * 16384, ub1 + tt * 128, ub2 + tt * 128);
    }
}